// Round 4
// baseline (237.433 us; speedup 1.0000x reference)
//
#include <hip/hip_runtime.h>
#include <math.h>

#define N_NODES 16384
#define D_MODEL 256
#define H_HEADS 4
#define C_CH 256
#define E_EDGES 65536
#define ETOT (E_EDGES + N_NODES)
#define HC 1024

typedef __bf16 bf16x8 __attribute__((ext_vector_type(8)));
typedef __bf16 bf16x4 __attribute__((ext_vector_type(4)));
typedef float f32x4 __attribute__((ext_vector_type(4)));

__device__ __forceinline__ __bf16 f2bf(float f) { return (__bf16)f; }
__device__ __forceinline__ float bf2f(__bf16 b) { return (float)b; }

// ---------------- fused weight cast: W1 | W_gat | W2 ----------------
__global__ __launch_bounds__(256) void cast_weights(
    const float* __restrict__ W1, const float* __restrict__ Wg,
    const float* __restrict__ W2, __bf16* __restrict__ o1,
    __bf16* __restrict__ og, __bf16* __restrict__ o2)
{
    int i = (blockIdx.x * 256 + threadIdx.x) * 4;
    const float* src; __bf16* dst; int off;
    if (i < 65536)            { src = W1; dst = o1; off = i; }
    else if (i < 65536+262144){ src = Wg; dst = og; off = i - 65536; }
    else                      { src = W2; dst = o2; off = i - 65536 - 262144; }
    float4 v = *(const float4*)(src + off);
    bf16x4 o;
    o[0] = f2bf(v.x); o[1] = f2bf(v.y); o[2] = f2bf(v.z); o[3] = f2bf(v.w);
    *(bf16x4*)(dst + off) = o;
}

// ------- u[v][d] = sum_c W_gat[h*256+c][d] * att[h][c];  v<4: src, v>=4: dst -------
__global__ __launch_bounds__(256) void make_u(
    const float* __restrict__ W_gat, const float* __restrict__ att_src,
    const float* __restrict__ att_dst, float* __restrict__ u)
{
    int v = blockIdx.x;          // 0..7
    int h = v & 3;
    int d = threadIdx.x;         // 0..255
    const float* att = (v < 4 ? att_src : att_dst) + h * C_CH;
    const float* Wp  = W_gat + (size_t)h * C_CH * D_MODEL + d;
    float acc = 0.f;
    #pragma unroll 8
    for (int c = 0; c < C_CH; ++c)
        acc = fmaf(Wp[(size_t)c * D_MODEL], att[c], acc);
    u[v * D_MODEL + d] = acc;
}

// ---------------- LayerNorm: one row per wave, bf16 out ----------------
__global__ __launch_bounds__(256) void ln_kernel(
    const float* __restrict__ in, const float* __restrict__ gamma,
    const float* __restrict__ beta, __bf16* __restrict__ out)
{
    int wave = threadIdx.x >> 6;
    int lane = threadIdx.x & 63;
    int row  = blockIdx.x * 4 + wave;
    float4 v = ((const float4*)(in + (size_t)row * D_MODEL))[lane];
    float s  = v.x + v.y + v.z + v.w;
    float sq = v.x*v.x + v.y*v.y + v.z*v.z + v.w*v.w;
    for (int off = 32; off; off >>= 1) {
        s  += __shfl_xor(s,  off);
        sq += __shfl_xor(sq, off);
    }
    float mean = s * (1.0f / D_MODEL);
    float var  = sq * (1.0f / D_MODEL) - mean * mean;
    float inv  = rsqrtf(var + 1e-6f);
    float4 g = ((const float4*)gamma)[lane];
    float4 b = ((const float4*)beta)[lane];
    bf16x4 o;
    o[0] = f2bf((v.x - mean) * inv * g.x + b.x);
    o[1] = f2bf((v.y - mean) * inv * g.y + b.y);
    o[2] = f2bf((v.z - mean) * inv * g.z + b.z);
    o[3] = f2bf((v.w - mean) * inv * g.w + b.w);
    *(bf16x4*)(out + (size_t)row * D_MODEL + lane * 4) = o;
}

// -------- bf16 MFMA GEMM: C[M,N] = A[M,K] * B[N,K]^T (+bias)(+resid) --------
#define BM 128
#define BN 128
#define BK 32
#define LDP 40   // LDS row stride (80B): max 2-way bank aliasing (free)

__global__ __launch_bounds__(256) void gemm_bf16_nt(
    const __bf16* __restrict__ A, const __bf16* __restrict__ B,
    int M, int N, int K,
    const float* __restrict__ bias, const float* __restrict__ resid,
    float* __restrict__ outf, __bf16* __restrict__ outb)
{
    __shared__ __bf16 As[BM * LDP];
    __shared__ __bf16 Bs[BN * LDP];
    int tid  = threadIdx.x;
    int lane = tid & 63;
    int w    = tid >> 6;
    int wm   = w >> 1, wn = w & 1;
    int quad = lane >> 4;
    int l16  = lane & 15;
    int m0 = blockIdx.y * BM;
    int n0 = blockIdx.x * BN;

    f32x4 acc[4][4] = {};

    for (int kb = 0; kb < K; kb += BK) {
        bf16x8 areg[2], breg[2];
        #pragma unroll
        for (int t = 0; t < 2; ++t) {
            int c = tid + t * 256;
            int r = c >> 2, p = c & 3;
            areg[t] = *(const bf16x8*)(A + (size_t)(m0 + r) * K + kb + p * 8);
            breg[t] = *(const bf16x8*)(B + (size_t)(n0 + r) * K + kb + p * 8);
        }
        __syncthreads();
        #pragma unroll
        for (int t = 0; t < 2; ++t) {
            int c = tid + t * 256;
            int r = c >> 2, p = c & 3;
            *(bf16x8*)(As + r * LDP + p * 8) = areg[t];
            *(bf16x8*)(Bs + r * LDP + p * 8) = breg[t];
        }
        __syncthreads();
        bf16x8 af[4], bfr[4];
        #pragma unroll
        for (int mt = 0; mt < 4; ++mt)
            af[mt] = *(const bf16x8*)(As + (wm * 64 + mt * 16 + l16) * LDP + quad * 8);
        #pragma unroll
        for (int nt = 0; nt < 4; ++nt)
            bfr[nt] = *(const bf16x8*)(Bs + (wn * 64 + nt * 16 + l16) * LDP + quad * 8);
        #pragma unroll
        for (int mt = 0; mt < 4; ++mt)
            #pragma unroll
            for (int nt = 0; nt < 4; ++nt)
                acc[mt][nt] = __builtin_amdgcn_mfma_f32_16x16x32_bf16(
                    af[mt], bfr[nt], acc[mt][nt], 0, 0, 0);
    }

    int rowb = m0 + wm * 64;
    int colb = n0 + wn * 64;
    #pragma unroll
    for (int nt = 0; nt < 4; ++nt) {
        int col = colb + nt * 16 + l16;
        float bv = bias ? bias[col] : 0.0f;
        #pragma unroll
        for (int mt = 0; mt < 4; ++mt) {
            int row = rowb + mt * 16 + quad * 4;
            #pragma unroll
            for (int r = 0; r < 4; ++r) {
                float v = acc[mt][nt][r] + bv;
                size_t off = (size_t)(row + r) * N + col;
                if (outf) {
                    if (resid) v += resid[off];
                    outf[off] = v;
                } else {
                    outb[off] = f2bf(v);
                }
            }
        }
    }
}

// ------- logits directly from gnn_in: a[n][v] = gnn_in[n,:] . u[v,:] -------
// wave per node; lane = (v<<3)|p ; p covers 32 channels
__global__ __launch_bounds__(256) void att_logits_direct(
    const __bf16* __restrict__ gnn_in, const float* __restrict__ u,
    float* __restrict__ a_src, float* __restrict__ a_dst)
{
    int wave = threadIdx.x >> 6, lane = threadIdx.x & 63;
    int n = blockIdx.x * 4 + wave;
    int v = lane >> 3, p = lane & 7;
    const __bf16* rp = gnn_in + (size_t)n * D_MODEL + p * 32;
    const float*  up = u + v * D_MODEL + p * 32;
    float acc = 0.f;
    #pragma unroll
    for (int t = 0; t < 4; ++t) {
        bf16x8 x = *(const bf16x8*)(rp + t * 8);
        #pragma unroll
        for (int j = 0; j < 8; ++j)
            acc = fmaf(bf2f(x[j]), up[t * 8 + j], acc);
    }
    acc += __shfl_xor(acc, 1);
    acc += __shfl_xor(acc, 2);
    acc += __shfl_xor(acc, 4);
    if (p == 0) {
        if (v < 4) a_src[n * H_HEADS + v] = acc;
        else       a_dst[n * H_HEADS + (v - 4)] = acc;
    }
}

// ---------------- CSR build ----------------
__global__ void hist_kernel(const int* __restrict__ ei, int* __restrict__ deg)
{
    int e = blockIdx.x * blockDim.x + threadIdx.x;
    if (e >= ETOT) return;
    int dst = (e < E_EDGES) ? ei[E_EDGES + e] : (e - E_EDGES);
    atomicAdd(deg + dst, 1);
}

// shfl-based scan: 1024 threads x 16 elems
__global__ __launch_bounds__(1024) void scan_kernel(
    const int* __restrict__ deg, int* __restrict__ row_start)
{
    __shared__ int wsum[16];
    int tid = threadIdx.x;
    int lane = tid & 63, wid = tid >> 6;
    int base = tid * 16;
    int local[16];
    int run = 0;
    #pragma unroll
    for (int j = 0; j < 16; ++j) { local[j] = run; run += deg[base + j]; }
    int x = run;
    #pragma unroll
    for (int off = 1; off < 64; off <<= 1) {
        int y = __shfl_up(x, off);
        if (lane >= off) x += y;
    }
    if (lane == 63) wsum[wid] = x;
    __syncthreads();
    if (wid == 0) {
        int wv = (lane < 16) ? wsum[lane] : 0;
        int xx = wv;
        #pragma unroll
        for (int off = 1; off < 16; off <<= 1) {
            int y = __shfl_up(xx, off);
            if (lane >= off) xx += y;
        }
        if (lane < 16) wsum[lane] = xx - wv;   // exclusive wave offsets
    }
    __syncthreads();
    int excl = wsum[wid] + (x - run);
    #pragma unroll
    for (int j = 0; j < 16; ++j) row_start[base + j] = excl + local[j];
    if (tid == 1023) row_start[N_NODES] = excl + run;
}

__global__ void scatter_kernel(const int* __restrict__ ei,
                               const int* __restrict__ row_start,
                               int* __restrict__ cnt, int* __restrict__ csr_src)
{
    int e = blockIdx.x * blockDim.x + threadIdx.x;
    if (e >= ETOT) return;
    int src, dst;
    if (e < E_EDGES) { src = ei[e]; dst = ei[E_EDGES + e]; }
    else             { src = dst = e - E_EDGES; }
    int pos = atomicAdd(cnt + dst, 1);
    csr_src[row_start[dst] + pos] = src;
}

// ------- per-node softmax: one WAVE per node; writes unnormalized alpha -------
__global__ __launch_bounds__(256) void node_softmax(
    const float* __restrict__ a_src, const float* __restrict__ a_dst,
    const int* __restrict__ row_start, const int* __restrict__ csr_src,
    float* __restrict__ alpha, float* __restrict__ inv_denom)
{
    int wave = threadIdx.x >> 6, lane = threadIdx.x & 63;
    int i = blockIdx.x * 4 + wave;
    int rs = row_start[i], deg = row_start[i + 1] - rs;
    float adst[H_HEADS];
    #pragma unroll
    for (int h = 0; h < H_HEADS; ++h) adst[h] = a_dst[i * H_HEADS + h];

    float mx[H_HEADS] = {-1e30f, -1e30f, -1e30f, -1e30f};
    for (int e = lane; e < deg; e += 64) {
        int s = csr_src[rs + e];
        float4 as = *(const float4*)(a_src + s * H_HEADS);
        float l[H_HEADS] = {as.x + adst[0], as.y + adst[1], as.z + adst[2], as.w + adst[3]};
        #pragma unroll
        for (int h = 0; h < H_HEADS; ++h) {
            float v = (l[h] > 0.f) ? l[h] : 0.2f * l[h];
            mx[h] = fmaxf(mx[h], v);
        }
    }
    #pragma unroll
    for (int h = 0; h < H_HEADS; ++h)
        for (int off = 32; off; off >>= 1) mx[h] = fmaxf(mx[h], __shfl_xor(mx[h], off));

    float sm[H_HEADS] = {0.f, 0.f, 0.f, 0.f};
    for (int e = lane; e < deg; e += 64) {
        int s = csr_src[rs + e];
        float4 as = *(const float4*)(a_src + s * H_HEADS);
        float l[H_HEADS] = {as.x + adst[0], as.y + adst[1], as.z + adst[2], as.w + adst[3]};
        float4 wv;
        #pragma unroll
        for (int h = 0; h < H_HEADS; ++h) {
            float v = (l[h] > 0.f) ? l[h] : 0.2f * l[h];
            float w = expf(v - mx[h]);
            sm[h] += w;
            ((float*)&wv)[h] = w;
        }
        *(float4*)(alpha + (size_t)(rs + e) * H_HEADS) = wv;
    }
    #pragma unroll
    for (int h = 0; h < H_HEADS; ++h)
        for (int off = 32; off; off >>= 1) sm[h] += __shfl_xor(sm[h], off);
    if (lane == 0) {
        #pragma unroll
        for (int h = 0; h < H_HEADS; ++h)
            inv_denom[i * H_HEADS + h] = 1.0f / sm[h];
    }
}

// ------- aggregation: 2 nodes per block; per node 128 threads x 16B loads -------
__global__ __launch_bounds__(256) void gat_aggregate(
    const __bf16* __restrict__ xh, const float* __restrict__ alpha,
    const float* __restrict__ inv_denom, const int* __restrict__ row_start,
    const int* __restrict__ csr_src, const float* __restrict__ bias,
    __bf16* __restrict__ out)
{
    __shared__ float sacc[2][H_HEADS][C_CH];   // 8 KB
    int tid = threadIdx.x;
    int sub = tid >> 7;            // node half
    int tl  = tid & 127;
    int h   = tl >> 5;
    int cih = (tl & 31) << 3;      // channel-in-head base (8 ch)
    int i = blockIdx.x * 2 + sub;
    int rs = row_start[i], deg = row_start[i + 1] - rs;

    float a[8] = {};
    for (int e = 0; e < deg; ++e) {
        int s = csr_src[rs + e];
        float w = alpha[(size_t)(rs + e) * H_HEADS + h];
        bf16x8 x = *(const bf16x8*)(xh + (size_t)s * HC + (h << 8) + cih);
        #pragma unroll
        for (int j = 0; j < 8; ++j) a[j] = fmaf(w, bf2f(x[j]), a[j]);
    }
    float sc = inv_denom[i * H_HEADS + h] * 0.25f;  // fold head-mean
    #pragma unroll
    for (int j = 0; j < 8; ++j) sacc[sub][h][cih + j] = a[j] * sc;
    __syncthreads();
    // 512 outputs / 256 threads: each thread 2 channels of its node
    float o0 = sacc[sub][0][tl] + sacc[sub][1][tl] + sacc[sub][2][tl] + sacc[sub][3][tl];
    int c1 = tl + 128;
    float o1 = sacc[sub][0][c1] + sacc[sub][1][c1] + sacc[sub][2][c1] + sacc[sub][3][c1];
    out[(size_t)i * C_CH + tl] = f2bf(o0 + bias[tl]);
    out[(size_t)i * C_CH + c1] = f2bf(o1 + bias[c1]);
}

extern "C" void kernel_launch(void* const* d_in, const int* in_sizes, int n_in,
                              void* d_out, int out_size, void* d_ws, size_t ws_size,
                              hipStream_t stream)
{
    const float* inp      = (const float*)d_in[0];
    const int*   ei       = (const int*)  d_in[1];
    const float* ln_gamma = (const float*)d_in[2];
    const float* ln_beta  = (const float*)d_in[3];
    const float* W1       = (const float*)d_in[4];
    const float* b1       = (const float*)d_in[5];
    const float* W_gat    = (const float*)d_in[6];
    const float* att_src  = (const float*)d_in[7];
    const float* att_dst  = (const float*)d_in[8];
    const float* bias_gat = (const float*)d_in[9];
    const float* W2       = (const float*)d_in[10];
    const float* b2       = (const float*)d_in[11];

    char* ws = (char*)d_ws;
    __bf16* x_ln_bf    = (__bf16*)(ws);                        //  8 MB
    __bf16* gnn_in_bf  = (__bf16*)(ws + (8ull  << 20));        //  8 MB
    __bf16* xh_bf      = (__bf16*)(ws + (16ull << 20));        // 32 MB
    __bf16* gnn_out_bf = (__bf16*)(ws + (48ull << 20));        //  8 MB
    __bf16* W1_bf      = (__bf16*)(ws + (56ull << 20));
    __bf16* Wgat_bf    = W1_bf + 65536;
    __bf16* W2_bf      = Wgat_bf + 262144;
    float*  a_src_b    = (float*)(ws + (57ull << 20));
    float*  a_dst_b    = a_src_b + (size_t)N_NODES * H_HEADS;
    float*  alpha      = a_dst_b + (size_t)N_NODES * H_HEADS;
    float*  inv_denom  = alpha + (size_t)ETOT * H_HEADS;
    float*  u_vec      = inv_denom + (size_t)N_NODES * H_HEADS;
    int*    deg        = (int*)(u_vec + 8 * D_MODEL);
    int*    cnt        = deg + N_NODES;                        // adjacent: one memset
    int*    row_st     = cnt + N_NODES;
    int*    csr_src    = row_st + N_NODES + 4;

    // prep: weight cast, u vectors, CSR build
    hipMemsetAsync(deg, 0, 2 * N_NODES * sizeof(int), stream);
    cast_weights<<<384, 256, 0, stream>>>(W1, W_gat, W2, W1_bf, Wgat_bf, W2_bf);
    make_u<<<8, 256, 0, stream>>>(W_gat, att_src, att_dst, u_vec);
    hist_kernel<<<(ETOT + 255) / 256, 256, 0, stream>>>(ei, deg);
    scan_kernel<<<1, 1024, 0, stream>>>(deg, row_st);
    scatter_kernel<<<(ETOT + 255) / 256, 256, 0, stream>>>(ei, row_st, cnt, csr_src);

    // dense pipeline
    ln_kernel<<<N_NODES / 4, 256, 0, stream>>>(inp, ln_gamma, ln_beta, x_ln_bf);
    gemm_bf16_nt<<<dim3(D_MODEL / BN, N_NODES / BM), 256, 0, stream>>>(
        x_ln_bf, W1_bf, N_NODES, D_MODEL, D_MODEL, b1, nullptr, nullptr, gnn_in_bf);
    att_logits_direct<<<N_NODES / 4, 256, 0, stream>>>(gnn_in_bf, u_vec, a_src_b, a_dst_b);
    node_softmax<<<N_NODES / 4, 256, 0, stream>>>(a_src_b, a_dst_b, row_st, csr_src,
                                                  alpha, inv_denom);
    gemm_bf16_nt<<<dim3(HC / BN, N_NODES / BM), 256, 0, stream>>>(
        gnn_in_bf, Wgat_bf, N_NODES, HC, D_MODEL, nullptr, nullptr, nullptr, xh_bf);
    gat_aggregate<<<N_NODES / 2, 256, 0, stream>>>(xh_bf, alpha, inv_denom, row_st,
                                                   csr_src, bias_gat, gnn_out_bf);
    gemm_bf16_nt<<<dim3(D_MODEL / BN, N_NODES / BM), 256, 0, stream>>>(
        gnn_out_bf, W2_bf, N_NODES, D_MODEL, D_MODEL, b2, inp, (float*)d_out, nullptr);
}

// Round 5
// 230.825 us; speedup vs baseline: 1.0286x; 1.0286x over previous
//
#include <hip/hip_runtime.h>
#include <math.h>

#define N_NODES 16384
#define D_MODEL 256
#define H_HEADS 4
#define C_CH 256
#define E_EDGES 65536
#define ETOT (E_EDGES + N_NODES)
#define HC 1024

typedef __bf16 bf16x8 __attribute__((ext_vector_type(8)));
typedef __bf16 bf16x4 __attribute__((ext_vector_type(4)));
typedef float f32x4 __attribute__((ext_vector_type(4)));

__device__ __forceinline__ __bf16 f2bf(float f) { return (__bf16)f; }
__device__ __forceinline__ float bf2f(__bf16 b) { return (float)b; }

// ---------------- W2 -> bf16 ----------------
__global__ __launch_bounds__(256) void cast_w2(const float* __restrict__ src,
                                               __bf16* __restrict__ dst)
{
    int i = (blockIdx.x * 256 + threadIdx.x) * 4;
    float4 v = *(const float4*)(src + i);
    bf16x4 o;
    o[0] = f2bf(v.x); o[1] = f2bf(v.y); o[2] = f2bf(v.z); o[3] = f2bf(v.w);
    *(bf16x4*)(dst + i) = o;
}

// ------- composite projection: Wc[o][d] = sum_c Wg[o][c] * W1[c][d] -------
// 4 output rows per block; also bias_c[o] = Wg[o,:]·b1
__global__ __launch_bounds__(256) void compose_wc(
    const float* __restrict__ Wg, const float* __restrict__ W1,
    const float* __restrict__ b1, float* __restrict__ Wc_f,
    __bf16* __restrict__ Wc_b, float* __restrict__ bias_c)
{
    int o0 = blockIdx.x * 4;
    int d  = threadIdx.x;
    const float* w0 = Wg + (size_t)o0 * 256;
    float acc0 = 0.f, acc1 = 0.f, acc2 = 0.f, acc3 = 0.f;
    #pragma unroll 4
    for (int c = 0; c < 256; ++c) {
        float w1v = W1[(size_t)c * 256 + d];
        acc0 = fmaf(w0[c],       w1v, acc0);
        acc1 = fmaf(w0[256 + c], w1v, acc1);
        acc2 = fmaf(w0[512 + c], w1v, acc2);
        acc3 = fmaf(w0[768 + c], w1v, acc3);
    }
    float accs[4] = {acc0, acc1, acc2, acc3};
    #pragma unroll
    for (int j = 0; j < 4; ++j) {
        size_t off = (size_t)(o0 + j) * 256 + d;
        Wc_f[off] = accs[j];
        Wc_b[off] = f2bf(accs[j]);
    }
    __shared__ float red[4][4];
    #pragma unroll
    for (int j = 0; j < 4; ++j) {
        float t = w0[j * 256 + d] * b1[d];
        for (int s = 32; s; s >>= 1) t += __shfl_xor(t, s);
        if ((d & 63) == 0) red[j][d >> 6] = t;
    }
    __syncthreads();
    if (d < 4) bias_c[o0 + d] = red[d][0] + red[d][1] + red[d][2] + red[d][3];
}

// ------- u2[v][d] = sum_cc Wc_f[(h*256+cc)][d] * att[h][cc]  (v<4 src, v>=4 dst)
// u2/c0 pre-zeroed; blocks 0..63 = (v, 32-cc slice) partials via atomicAdd;
// block 64 computes c0[v] = bias_c[h-slice]·att.
__global__ __launch_bounds__(256) void make_u2(
    const float* __restrict__ Wc_f, const float* __restrict__ bias_c,
    const float* __restrict__ att_src, const float* __restrict__ att_dst,
    float* __restrict__ u2, float* __restrict__ c0)
{
    int b = blockIdx.x;
    if (b < 64) {
        int v = b >> 3, sl = b & 7;
        int h = v & 3;
        const float* att = ((v < 4) ? att_src : att_dst) + h * C_CH;
        int d = threadIdx.x;
        float acc = 0.f;
        #pragma unroll
        for (int j = 0; j < 32; ++j) {
            int cc = sl * 32 + j;
            acc = fmaf(Wc_f[(size_t)(h * 256 + cc) * 256 + d], att[cc], acc);
        }
        atomicAdd(&u2[v * 256 + d], acc);
    } else {
        int tid = threadIdx.x;
        int v = tid >> 5, l = tid & 31;
        int h = v & 3;
        const float* att = ((v < 4) ? att_src : att_dst) + h * C_CH;
        float t = 0.f;
        #pragma unroll
        for (int j = 0; j < 8; ++j) {
            int cc = l * 8 + j;
            t = fmaf(bias_c[h * 256 + cc], att[cc], t);
        }
        for (int s = 1; s < 32; s <<= 1) t += __shfl_xor(t, s);
        if (l == 0) c0[v] = t;
    }
}

// ------- LayerNorm + fused attention logits: one row per wave -------
__global__ __launch_bounds__(256) void ln_logits(
    const float* __restrict__ in, const float* __restrict__ gamma,
    const float* __restrict__ beta, const float* __restrict__ u2,
    const float* __restrict__ c0, __bf16* __restrict__ out,
    float* __restrict__ a_src, float* __restrict__ a_dst)
{
    __shared__ float u2s[8][256];
    __shared__ float c0s[8];
    int tid = threadIdx.x;
    #pragma unroll
    for (int t = 0; t < 8; ++t) u2s[t][tid] = u2[t * 256 + tid];
    if (tid < 8) c0s[tid] = c0[tid];
    __syncthreads();

    int wave = tid >> 6, lane = tid & 63;
    int row = blockIdx.x * 4 + wave;
    float4 v = ((const float4*)(in + (size_t)row * D_MODEL))[lane];
    float s  = v.x + v.y + v.z + v.w;
    float sq = v.x*v.x + v.y*v.y + v.z*v.z + v.w*v.w;
    for (int off = 32; off; off >>= 1) {
        s  += __shfl_xor(s,  off);
        sq += __shfl_xor(sq, off);
    }
    float mean = s * (1.0f / D_MODEL);
    float var  = sq * (1.0f / D_MODEL) - mean * mean;
    float inv  = rsqrtf(var + 1e-6f);
    float4 g = ((const float4*)gamma)[lane];
    float4 b = ((const float4*)beta)[lane];
    float x0 = (v.x - mean) * inv * g.x + b.x;
    float x1 = (v.y - mean) * inv * g.y + b.y;
    float x2 = (v.z - mean) * inv * g.z + b.z;
    float x3 = (v.w - mean) * inv * g.w + b.w;
    bf16x4 o;
    o[0] = f2bf(x0); o[1] = f2bf(x1); o[2] = f2bf(x2); o[3] = f2bf(x3);
    *(bf16x4*)(out + (size_t)row * D_MODEL + lane * 4) = o;

    // 8 fp32 dots against u2 (exact fp32 logits path)
    float p[8];
    #pragma unroll
    for (int k = 0; k < 8; ++k) {
        const float* up = &u2s[k][lane * 4];
        p[k] = x0 * up[0] + x1 * up[1] + x2 * up[2] + x3 * up[3];
    }
    #pragma unroll
    for (int k = 0; k < 8; ++k)
        for (int s2 = 32; s2; s2 >>= 1) p[k] += __shfl_xor(p[k], s2);
    if (lane == 0) {
        f32x4 ps = {p[0] + c0s[0], p[1] + c0s[1], p[2] + c0s[2], p[3] + c0s[3]};
        f32x4 pd = {p[4] + c0s[4], p[5] + c0s[5], p[6] + c0s[6], p[7] + c0s[7]};
        *(f32x4*)(a_src + row * H_HEADS) = ps;
        *(f32x4*)(a_dst + row * H_HEADS) = pd;
    }
}

// -------- bf16 MFMA GEMM: C[M,N] = A[M,K] * B[N,K]^T (+bias)(+resid) --------
#define BM 128
#define BN 128
#define BK 32
#define LDP 40   // LDS row stride (80B): max 2-way bank aliasing (free)

__global__ __launch_bounds__(256) void gemm_bf16_nt(
    const __bf16* __restrict__ A, const __bf16* __restrict__ B,
    int M, int N, int K,
    const float* __restrict__ bias, const float* __restrict__ resid,
    float* __restrict__ outf, __bf16* __restrict__ outb)
{
    __shared__ __bf16 As[BM * LDP];
    __shared__ __bf16 Bs[BN * LDP];
    int tid  = threadIdx.x;
    int lane = tid & 63;
    int w    = tid >> 6;
    int wm   = w >> 1, wn = w & 1;
    int quad = lane >> 4;
    int l16  = lane & 15;
    int m0 = blockIdx.y * BM;
    int n0 = blockIdx.x * BN;

    f32x4 acc[4][4] = {};

    for (int kb = 0; kb < K; kb += BK) {
        bf16x8 areg[2], breg[2];
        #pragma unroll
        for (int t = 0; t < 2; ++t) {
            int c = tid + t * 256;
            int r = c >> 2, p = c & 3;
            areg[t] = *(const bf16x8*)(A + (size_t)(m0 + r) * K + kb + p * 8);
            breg[t] = *(const bf16x8*)(B + (size_t)(n0 + r) * K + kb + p * 8);
        }
        __syncthreads();
        #pragma unroll
        for (int t = 0; t < 2; ++t) {
            int c = tid + t * 256;
            int r = c >> 2, p = c & 3;
            *(bf16x8*)(As + r * LDP + p * 8) = areg[t];
            *(bf16x8*)(Bs + r * LDP + p * 8) = breg[t];
        }
        __syncthreads();
        bf16x8 af[4], bfr[4];
        #pragma unroll
        for (int mt = 0; mt < 4; ++mt)
            af[mt] = *(const bf16x8*)(As + (wm * 64 + mt * 16 + l16) * LDP + quad * 8);
        #pragma unroll
        for (int nt = 0; nt < 4; ++nt)
            bfr[nt] = *(const bf16x8*)(Bs + (wn * 64 + nt * 16 + l16) * LDP + quad * 8);
        #pragma unroll
        for (int mt = 0; mt < 4; ++mt)
            #pragma unroll
            for (int nt = 0; nt < 4; ++nt)
                acc[mt][nt] = __builtin_amdgcn_mfma_f32_16x16x32_bf16(
                    af[mt], bfr[nt], acc[mt][nt], 0, 0, 0);
    }

    int rowb = m0 + wm * 64;
    int colb = n0 + wn * 64;
    #pragma unroll
    for (int nt = 0; nt < 4; ++nt) {
        int col = colb + nt * 16 + l16;
        float bv = bias ? bias[col] : 0.0f;
        #pragma unroll
        for (int mt = 0; mt < 4; ++mt) {
            int row = rowb + mt * 16 + quad * 4;
            #pragma unroll
            for (int r = 0; r < 4; ++r) {
                float v = acc[mt][nt][r] + bv;
                size_t off = (size_t)(row + r) * N + col;
                if (outf) {
                    if (resid) v += resid[off];
                    outf[off] = v;
                } else {
                    outb[off] = f2bf(v);
                }
            }
        }
    }
}

// ---------------- CSR build ----------------
__global__ void hist_kernel(const int* __restrict__ ei, int* __restrict__ deg)
{
    int e = blockIdx.x * blockDim.x + threadIdx.x;
    if (e >= ETOT) return;
    int dst = (e < E_EDGES) ? ei[E_EDGES + e] : (e - E_EDGES);
    atomicAdd(deg + dst, 1);
}

__global__ __launch_bounds__(1024) void scan_kernel(
    const int* __restrict__ deg, int* __restrict__ row_start)
{
    __shared__ int wsum[16];
    int tid = threadIdx.x;
    int lane = tid & 63, wid = tid >> 6;
    int base = tid * 16;
    int local[16];
    int run = 0;
    #pragma unroll
    for (int j = 0; j < 16; ++j) { local[j] = run; run += deg[base + j]; }
    int x = run;
    #pragma unroll
    for (int off = 1; off < 64; off <<= 1) {
        int y = __shfl_up(x, off);
        if (lane >= off) x += y;
    }
    if (lane == 63) wsum[wid] = x;
    __syncthreads();
    if (wid == 0) {
        int wv = (lane < 16) ? wsum[lane] : 0;
        int xx = wv;
        #pragma unroll
        for (int off = 1; off < 16; off <<= 1) {
            int y = __shfl_up(xx, off);
            if (lane >= off) xx += y;
        }
        if (lane < 16) wsum[lane] = xx - wv;
    }
    __syncthreads();
    int excl = wsum[wid] + (x - run);
    #pragma unroll
    for (int j = 0; j < 16; ++j) row_start[base + j] = excl + local[j];
    if (tid == 1023) row_start[N_NODES] = excl + run;
}

__global__ void scatter_kernel(const int* __restrict__ ei,
                               const int* __restrict__ row_start,
                               int* __restrict__ cnt, int* __restrict__ csr_src)
{
    int e = blockIdx.x * blockDim.x + threadIdx.x;
    if (e >= ETOT) return;
    int src, dst;
    if (e < E_EDGES) { src = ei[e]; dst = ei[E_EDGES + e]; }
    else             { src = dst = e - E_EDGES; }
    int pos = atomicAdd(cnt + dst, 1);
    csr_src[row_start[dst] + pos] = src;
}

// ------- per-node softmax: one WAVE per node; writes unnormalized alpha -------
__global__ __launch_bounds__(256) void node_softmax(
    const float* __restrict__ a_src, const float* __restrict__ a_dst,
    const int* __restrict__ row_start, const int* __restrict__ csr_src,
    float* __restrict__ alpha, float* __restrict__ inv_denom)
{
    int wave = threadIdx.x >> 6, lane = threadIdx.x & 63;
    int i = blockIdx.x * 4 + wave;
    int rs = row_start[i], deg = row_start[i + 1] - rs;
    float adst[H_HEADS];
    #pragma unroll
    for (int h = 0; h < H_HEADS; ++h) adst[h] = a_dst[i * H_HEADS + h];

    float mx[H_HEADS] = {-1e30f, -1e30f, -1e30f, -1e30f};
    for (int e = lane; e < deg; e += 64) {
        int s = csr_src[rs + e];
        float4 as = *(const float4*)(a_src + s * H_HEADS);
        float l[H_HEADS] = {as.x + adst[0], as.y + adst[1], as.z + adst[2], as.w + adst[3]};
        #pragma unroll
        for (int h = 0; h < H_HEADS; ++h) {
            float v = (l[h] > 0.f) ? l[h] : 0.2f * l[h];
            mx[h] = fmaxf(mx[h], v);
        }
    }
    #pragma unroll
    for (int h = 0; h < H_HEADS; ++h)
        for (int off = 32; off; off >>= 1) mx[h] = fmaxf(mx[h], __shfl_xor(mx[h], off));

    float sm[H_HEADS] = {0.f, 0.f, 0.f, 0.f};
    for (int e = lane; e < deg; e += 64) {
        int s = csr_src[rs + e];
        float4 as = *(const float4*)(a_src + s * H_HEADS);
        float l[H_HEADS] = {as.x + adst[0], as.y + adst[1], as.z + adst[2], as.w + adst[3]};
        float4 wv;
        #pragma unroll
        for (int h = 0; h < H_HEADS; ++h) {
            float v = (l[h] > 0.f) ? l[h] : 0.2f * l[h];
            float w = expf(v - mx[h]);
            sm[h] += w;
            ((float*)&wv)[h] = w;
        }
        *(float4*)(alpha + (size_t)(rs + e) * H_HEADS) = wv;
    }
    #pragma unroll
    for (int h = 0; h < H_HEADS; ++h)
        for (int off = 32; off; off >>= 1) sm[h] += __shfl_xor(sm[h], off);
    if (lane == 0) {
        #pragma unroll
        for (int h = 0; h < H_HEADS; ++h)
            inv_denom[i * H_HEADS + h] = 1.0f / sm[h];
    }
}

// ------- aggregation: 2 nodes per block; per node 128 threads x 16B loads -------
__global__ __launch_bounds__(256) void gat_aggregate(
    const __bf16* __restrict__ xh, const float* __restrict__ alpha,
    const float* __restrict__ inv_denom, const int* __restrict__ row_start,
    const int* __restrict__ csr_src, const float* __restrict__ bias,
    __bf16* __restrict__ out)
{
    __shared__ float sacc[2][H_HEADS][C_CH];   // 8 KB
    int tid = threadIdx.x;
    int sub = tid >> 7;
    int tl  = tid & 127;
    int h   = tl >> 5;
    int cih = (tl & 31) << 3;
    int i = blockIdx.x * 2 + sub;
    int rs = row_start[i], deg = row_start[i + 1] - rs;

    float a[8] = {};
    for (int e = 0; e < deg; ++e) {
        int s = csr_src[rs + e];
        float w = alpha[(size_t)(rs + e) * H_HEADS + h];
        bf16x8 x = *(const bf16x8*)(xh + (size_t)s * HC + (h << 8) + cih);
        #pragma unroll
        for (int j = 0; j < 8; ++j) a[j] = fmaf(w, bf2f(x[j]), a[j]);
    }
    float sc = inv_denom[i * H_HEADS + h] * 0.25f;
    #pragma unroll
    for (int j = 0; j < 8; ++j) sacc[sub][h][cih + j] = a[j] * sc;
    __syncthreads();
    float o0 = sacc[sub][0][tl] + sacc[sub][1][tl] + sacc[sub][2][tl] + sacc[sub][3][tl];
    int c1 = tl + 128;
    float o1 = sacc[sub][0][c1] + sacc[sub][1][c1] + sacc[sub][2][c1] + sacc[sub][3][c1];
    out[(size_t)i * C_CH + tl] = f2bf(o0 + bias[tl]);
    out[(size_t)i * C_CH + c1] = f2bf(o1 + bias[c1]);
}

extern "C" void kernel_launch(void* const* d_in, const int* in_sizes, int n_in,
                              void* d_out, int out_size, void* d_ws, size_t ws_size,
                              hipStream_t stream)
{
    const float* inp      = (const float*)d_in[0];
    const int*   ei       = (const int*)  d_in[1];
    const float* ln_gamma = (const float*)d_in[2];
    const float* ln_beta  = (const float*)d_in[3];
    const float* W1       = (const float*)d_in[4];
    const float* b1       = (const float*)d_in[5];
    const float* W_gat    = (const float*)d_in[6];
    const float* att_src  = (const float*)d_in[7];
    const float* att_dst  = (const float*)d_in[8];
    const float* bias_gat = (const float*)d_in[9];
    const float* W2       = (const float*)d_in[10];
    const float* b2       = (const float*)d_in[11];

    char* ws = (char*)d_ws;
    __bf16* x_ln_bf    = (__bf16*)(ws);                        //  8 MB
    __bf16* xh_bf      = (__bf16*)(ws + (8ull  << 20));        // 32 MB
    __bf16* gnn_out_bf = (__bf16*)(ws + (40ull << 20));        //  8 MB
    __bf16* W2_bf      = (__bf16*)(ws + (48ull << 20));        // 128 KB
    __bf16* Wc_b       = W2_bf + 65536;                        // 512 KB
    float*  Wc_f       = (float*)(ws + (49ull << 20));         //   1 MB
    float*  bias_c     = (float*)(ws + (50ull << 20));         //   4 KB
    float*  a_src_b    = bias_c + 1024;
    float*  a_dst_b    = a_src_b + (size_t)N_NODES * H_HEADS;
    float*  alpha      = a_dst_b + (size_t)N_NODES * H_HEADS;
    float*  inv_denom  = alpha + (size_t)ETOT * H_HEADS;
    float*  u2         = inv_denom + (size_t)N_NODES * H_HEADS;  // zero-region start
    float*  c0         = u2 + 8 * D_MODEL;
    int*    deg        = (int*)(c0 + 8);
    int*    cnt        = deg + N_NODES;
    int*    row_st     = cnt + N_NODES;
    int*    csr_src    = row_st + N_NODES + 4;

    // zero u2|c0|deg|cnt in one shot
    size_t zbytes = (8 * D_MODEL + 8) * sizeof(float) + 2 * N_NODES * sizeof(int);
    hipMemsetAsync(u2, 0, zbytes, stream);

    // prep: composite weights, u2/c0, CSR
    cast_w2<<<64, 256, 0, stream>>>(W2, W2_bf);
    compose_wc<<<256, 256, 0, stream>>>(W_gat, W1, b1, Wc_f, Wc_b, bias_c);
    make_u2<<<65, 256, 0, stream>>>(Wc_f, bias_c, att_src, att_dst, u2, c0);
    hist_kernel<<<(ETOT + 255) / 256, 256, 0, stream>>>(ei, deg);
    scan_kernel<<<1, 1024, 0, stream>>>(deg, row_st);
    scatter_kernel<<<(ETOT + 255) / 256, 256, 0, stream>>>(ei, row_st, cnt, csr_src);

    // dense pipeline
    ln_logits<<<N_NODES / 4, 256, 0, stream>>>(inp, ln_gamma, ln_beta, u2, c0,
                                               x_ln_bf, a_src_b, a_dst_b);
    node_softmax<<<N_NODES / 4, 256, 0, stream>>>(a_src_b, a_dst_b, row_st, csr_src,
                                                  alpha, inv_denom);
    gemm_bf16_nt<<<dim3(HC / BN, N_NODES / BM), 256, 0, stream>>>(
        x_ln_bf, Wc_b, N_NODES, HC, D_MODEL, bias_c, nullptr, nullptr, xh_bf);
    gat_aggregate<<<N_NODES / 2, 256, 0, stream>>>(xh_bf, alpha, inv_denom, row_st,
                                                   csr_src, bias_gat, gnn_out_bf);
    gemm_bf16_nt<<<dim3(D_MODEL / BN, N_NODES / BM), 256, 0, stream>>>(
        gnn_out_bf, W2_bf, N_NODES, D_MODEL, D_MODEL, b2, inp, (float*)d_out, nullptr);
}